// Round 1
// baseline (946.480 us; speedup 1.0000x reference)
//
#include <hip/hip_runtime.h>
#include <cstdint>
#include <cstddef>

#define B_  64
#define D_  128
#define LC_ 1024
#define LQ_ 128
#define NEGV (-1e30f)
#define NINF (-3.402823466e38f)

// ---------------------------------------------------------------------------
// k0: s_q[b,q] = sum_d Q[b,d,q]*w[d];  s_c[b,c] = sum_d C[b,d,c]*w[D+d]
// ---------------------------------------------------------------------------
__global__ __launch_bounds__(256) void k0_sq(const float* __restrict__ Q,
                                             const float* __restrict__ w,
                                             float* __restrict__ sq_g) {
    int idx = blockIdx.x * 256 + threadIdx.x;     // < B*LQ = 8192
    int b = idx >> 7, q = idx & 127;
    float s = 0.f;
    for (int d = 0; d < D_; d++) s += Q[((size_t)b * D_ + d) * LQ_ + q] * w[d];
    sq_g[idx] = s;
}

__global__ __launch_bounds__(256) void k0_sc(const float* __restrict__ C,
                                             const float* __restrict__ w,
                                             float* __restrict__ sc_g) {
    int idx = blockIdx.x * 256 + threadIdx.x;     // < B*LC = 65536
    int b = idx >> 10, c = idx & 1023;
    float s = 0.f;
    for (int d = 0; d < D_; d++) s += C[((size_t)b * D_ + d) * LC_ + c] * w[D_ + d];
    sc_g[idx] = s;
}

// ---------------------------------------------------------------------------
// k1: S[b,c,q] = sum_d (w_m[d]*C[b,d,c])*Q[b,d,q] + s_c[b,c] + s_q[b,q]
//     also writes rowmax/rowsum (softmax over q, with qmask) per (b,c).
// Block: 256 thr handles (b, 32 c-rows x all 128 q). thread: c=t>>3, 16 q's.
// ---------------------------------------------------------------------------
__global__ __launch_bounds__(256) void k1_S(const float* __restrict__ C,
                                            const float* __restrict__ Q,
                                            const float* __restrict__ qmask,
                                            const float* __restrict__ w,
                                            const float* __restrict__ sc_g,
                                            const float* __restrict__ sq_g,
                                            float* __restrict__ S_g,
                                            float* __restrict__ rowmax_g,
                                            float* __restrict__ rowsum_g) {
    __shared__ float CW[32][33];
    __shared__ float Qc[32][128];
    __shared__ float wm_l[128];
    __shared__ float qm_l[128];
    __shared__ float sq_l[128];
    __shared__ float red[32][8];
    __shared__ float rms[32];

    int t = threadIdx.x;
    int b = blockIdx.y;
    int c0 = blockIdx.x * 32;
    if (t < 128) {
        wm_l[t] = w[2 * D_ + t];
        qm_l[t] = qmask[b * LQ_ + t];
        sq_l[t] = sq_g[b * LQ_ + t];
    }
    int c = t >> 3;          // 0..31
    int qsub = t & 7;        // 0..7 ; q = qsub*4 + 32*jj + k
    float acc[16];
#pragma unroll
    for (int j = 0; j < 16; j++) acc[j] = 0.f;
    __syncthreads();

    for (int d0 = 0; d0 < D_; d0 += 32) {
#pragma unroll
        for (int i = 0; i < 4; i++) {
            int lin = t + 256 * i;
            int dd = lin >> 5, cc = lin & 31;
            CW[dd][cc] = C[((size_t)b * D_ + d0 + dd) * LC_ + c0 + cc] * wm_l[d0 + dd];
        }
#pragma unroll
        for (int i = 0; i < 16; i++) {
            int lin = t + 256 * i;
            int dd = lin >> 7, q = lin & 127;
            Qc[dd][q] = Q[((size_t)b * D_ + d0 + dd) * LQ_ + q];
        }
        __syncthreads();
#pragma unroll
        for (int dd = 0; dd < 32; dd++) {
            float cw = CW[dd][c];
#pragma unroll
            for (int jj = 0; jj < 4; jj++) {
#pragma unroll
                for (int k = 0; k < 4; k++)
                    acc[jj * 4 + k] += cw * Qc[dd][qsub * 4 + 32 * jj + k];
            }
        }
        __syncthreads();
    }

    float scv = sc_g[b * LC_ + c0 + c];
    float sv[16];
#pragma unroll
    for (int jj = 0; jj < 4; jj++)
#pragma unroll
        for (int k = 0; k < 4; k++) {
            int q = qsub * 4 + 32 * jj + k;
            sv[jj * 4 + k] = acc[jj * 4 + k] + scv + sq_l[q];
        }

    size_t rowbase = ((size_t)b * LC_ + c0 + c) * LQ_;
#pragma unroll
    for (int jj = 0; jj < 4; jj++) {
        float4 v = make_float4(sv[jj * 4 + 0], sv[jj * 4 + 1], sv[jj * 4 + 2], sv[jj * 4 + 3]);
        *reinterpret_cast<float4*>(&S_g[rowbase + qsub * 4 + 32 * jj]) = v;
    }

    // row stats over masked values  Sm1 = S + (1-qmask[q])*NEG
    float lmax = NINF;
#pragma unroll
    for (int jj = 0; jj < 4; jj++)
#pragma unroll
        for (int k = 0; k < 4; k++) {
            int q = qsub * 4 + 32 * jj + k;
            float vm = sv[jj * 4 + k] + (1.0f - qm_l[q]) * NEGV;
            lmax = fmaxf(lmax, vm);
        }
    red[c][qsub] = lmax;
    __syncthreads();
    if (qsub == 0) {
        float m = red[c][0];
#pragma unroll
        for (int j = 1; j < 8; j++) m = fmaxf(m, red[c][j]);
        rms[c] = m;
    }
    __syncthreads();
    float rm = rms[c];
    float lsum = 0.f;
#pragma unroll
    for (int jj = 0; jj < 4; jj++)
#pragma unroll
        for (int k = 0; k < 4; k++) {
            int q = qsub * 4 + 32 * jj + k;
            float vm = sv[jj * 4 + k] + (1.0f - qm_l[q]) * NEGV;
            lsum += __expf(vm - rm);
        }
    __syncthreads();
    red[c][qsub] = lsum;
    __syncthreads();
    if (qsub == 0) {
        float s = 0.f;
#pragma unroll
        for (int j = 0; j < 8; j++) s += red[c][j];
        rowmax_g[b * LC_ + c0 + c] = rm;
        rowsum_g[b * LC_ + c0 + c] = s;
    }
}

// ---------------------------------------------------------------------------
// k2a/k2b: column softmax stats (over c, with cmask) -> colmax/colsum per (b,q)
// ---------------------------------------------------------------------------
__global__ __launch_bounds__(128) void k2a(const float* __restrict__ S_g,
                                           const float* __restrict__ cmask,
                                           float* __restrict__ pmax,
                                           float* __restrict__ psum) {
    int q = threadIdx.x;
    int b = blockIdx.y;
    int chunk = blockIdx.x;           // 32 chunks of 32 c
    int cbase = chunk * 32;
    float m = NINF, s = 0.f;
    for (int cc = 0; cc < 32; cc++) {
        int c = cbase + cc;
        float v = S_g[((size_t)b * LC_ + c) * LQ_ + q] + (1.0f - cmask[b * LC_ + c]) * NEGV;
        float mn = fmaxf(m, v);
        s = s * __expf(m - mn) + __expf(v - mn);
        m = mn;
    }
    pmax[((size_t)b * 32 + chunk) * LQ_ + q] = m;
    psum[((size_t)b * 32 + chunk) * LQ_ + q] = s;
}

__global__ __launch_bounds__(128) void k2b(const float* __restrict__ pmax,
                                           const float* __restrict__ psum,
                                           float* __restrict__ colmax_g,
                                           float* __restrict__ colsum_g) {
    int q = threadIdx.x;
    int b = blockIdx.x;
    float m = NINF;
    for (int j = 0; j < 32; j++) m = fmaxf(m, pmax[((size_t)b * 32 + j) * LQ_ + q]);
    float s = 0.f;
    for (int j = 0; j < 32; j++)
        s += psum[((size_t)b * 32 + j) * LQ_ + q] * __expf(pmax[((size_t)b * 32 + j) * LQ_ + q] - m);
    colmax_g[b * LQ_ + q] = m;
    colsum_g[b * LQ_ + q] = s;
}

// ---------------------------------------------------------------------------
// k3: T2[b,d,q] = (sum_c exp(S+cmaskterm - colmax[q]) * C[b,d,c]) / colsum[q]
// Grid (4 q-chunks, B). Block 256: thread qq=t&31, dbase=t>>5, 16 d's.
// ---------------------------------------------------------------------------
__global__ __launch_bounds__(256) void k3_T2(const float* __restrict__ C,
                                             const float* __restrict__ S_g,
                                             const float* __restrict__ cmask,
                                             const float* __restrict__ colmax_g,
                                             const float* __restrict__ colsum_g,
                                             float* __restrict__ T2_g) {
    __shared__ float Et[32][33];     // [qq][cc]
    __shared__ float Cl[128][33];    // [d][cc]
    __shared__ float cm_l[32];

    int t = threadIdx.x;
    int b = blockIdx.y;
    int q0 = blockIdx.x * 32;
    if (t < 32) cm_l[t] = colmax_g[b * LQ_ + q0 + t];
    int qq = t & 31;
    int dbase = t >> 5;   // 0..7
    float acc[16];
#pragma unroll
    for (int i = 0; i < 16; i++) acc[i] = 0.f;
    __syncthreads();

    for (int cb = 0; cb < LC_; cb += 32) {
        {
            int cc = t >> 3;            // 0..31
            int k4 = (t & 7) * 4;       // 0..28
            float4 v = *reinterpret_cast<const float4*>(
                &S_g[((size_t)b * LC_ + cb + cc) * LQ_ + q0 + k4]);
            float cmv = (1.0f - cmask[b * LC_ + cb + cc]) * NEGV;
            Et[k4 + 0][cc] = __expf(v.x + cmv - cm_l[k4 + 0]);
            Et[k4 + 1][cc] = __expf(v.y + cmv - cm_l[k4 + 1]);
            Et[k4 + 2][cc] = __expf(v.z + cmv - cm_l[k4 + 2]);
            Et[k4 + 3][cc] = __expf(v.w + cmv - cm_l[k4 + 3]);
        }
#pragma unroll
        for (int i = 0; i < 16; i++) {
            int lin = t + 256 * i;
            int dd = lin >> 5, cc = lin & 31;
            Cl[dd][cc] = C[((size_t)b * D_ + dd) * LC_ + cb + cc];
        }
        __syncthreads();
        float ereg[32];
#pragma unroll
        for (int cc = 0; cc < 32; cc++) ereg[cc] = Et[qq][cc];
#pragma unroll
        for (int i = 0; i < 16; i++) {
            int d = dbase + 8 * i;
            float a = 0.f;
#pragma unroll
            for (int cc = 0; cc < 32; cc++) a += ereg[cc] * Cl[d][cc];
            acc[i] += a;
        }
        __syncthreads();
    }

    float csinv = 1.0f / colsum_g[b * LQ_ + q0 + qq];
#pragma unroll
    for (int i = 0; i < 16; i++) {
        int d = dbase + 8 * i;
        T2_g[((size_t)b * D_ + d) * LQ_ + q0 + qq] = acc[i] * csinv;
    }
}

// ---------------------------------------------------------------------------
// k4: A^T[d,c] = (sum_q E1[c,q]*Q[d,q])/rowsum[c];
//     Bt^T[d,c] = (sum_q E1[c,q]*T2[d,q])/rowsum[c];
//     out[b] = [C ; A^T ; C.*A^T ; C.*Bt^T]  (feature-major, coalesced stores)
// Grid (16 c-tiles of 64, B). Block 256: cc=t&63 (lane->c), dgrp=t>>6, 32 d's.
// ---------------------------------------------------------------------------
__global__ __launch_bounds__(256) void k4_out(const float* __restrict__ C,
                                              const float* __restrict__ Q,
                                              const float* __restrict__ qmask,
                                              const float* __restrict__ S_g,
                                              const float* __restrict__ rowmax_g,
                                              const float* __restrict__ rowsum_g,
                                              const float* __restrict__ T2_g,
                                              float* __restrict__ out) {
    __shared__ float Qc[128][33];
    __shared__ float Tc[128][33];
    __shared__ float S1c[64][33];
    __shared__ float qm_l[128];
    __shared__ float rm_l[64];
    __shared__ float ri_l[64];

    int t = threadIdx.x;
    int b = blockIdx.y;
    int c0 = blockIdx.x * 64;
    if (t < 128) qm_l[t] = qmask[b * LQ_ + t];
    if (t < 64) {
        rm_l[t] = rowmax_g[b * LC_ + c0 + t];
        ri_l[t] = 1.0f / rowsum_g[b * LC_ + c0 + t];
    }
    int cc = t & 63;
    int dgrp = t >> 6;    // 0..3, wave-uniform
    float accA[32], accB[32];
#pragma unroll
    for (int i = 0; i < 32; i++) { accA[i] = 0.f; accB[i] = 0.f; }
    __syncthreads();

    for (int qq0 = 0; qq0 < LQ_; qq0 += 32) {
#pragma unroll
        for (int i = 0; i < 16; i++) {
            int lin = t + 256 * i;
            int dd = lin >> 5, qq = lin & 31;
            Qc[dd][qq] = Q[((size_t)b * D_ + dd) * LQ_ + qq0 + qq];
            Tc[dd][qq] = T2_g[((size_t)b * D_ + dd) * LQ_ + qq0 + qq];
        }
#pragma unroll
        for (int i = 0; i < 8; i++) {
            int lin = t + 256 * i;
            int r = lin >> 5, qq = lin & 31;
            float v = S_g[((size_t)b * LC_ + c0 + r) * LQ_ + qq0 + qq];
            float vm = v + (1.0f - qm_l[qq0 + qq]) * NEGV;
            S1c[r][qq] = __expf(vm - rm_l[r]);
        }
        __syncthreads();
        float sreg[32];
#pragma unroll
        for (int qq = 0; qq < 32; qq++) sreg[qq] = S1c[cc][qq];
#pragma unroll
        for (int i = 0; i < 32; i++) {
            int d = dgrp * 32 + i;
            float a = 0.f, bt = 0.f;
#pragma unroll
            for (int qq = 0; qq < 32; qq++) {
                a  += sreg[qq] * Qc[d][qq];
                bt += sreg[qq] * Tc[d][qq];
            }
            accA[i] += a;
            accB[i] += bt;
        }
        __syncthreads();
    }

    float ri = ri_l[cc];
#pragma unroll
    for (int i = 0; i < 32; i++) {
        int d = dgrp * 32 + i;
        float cv = C[((size_t)b * D_ + d) * LC_ + c0 + cc];   // coalesced across cc
        float a = accA[i] * ri;
        float bt = accB[i] * ri;
        size_t ob = ((size_t)b * (4 * D_) + d) * LC_ + c0 + cc;
        out[ob] = cv;
        out[ob + (size_t)1 * D_ * LC_] = a;
        out[ob + (size_t)2 * D_ * LC_] = cv * a;
        out[ob + (size_t)3 * D_ * LC_] = cv * bt;
    }
}

// ---------------------------------------------------------------------------
extern "C" void kernel_launch(void* const* d_in, const int* in_sizes, int n_in,
                              void* d_out, int out_size, void* d_ws, size_t ws_size,
                              hipStream_t stream) {
    const float* C     = (const float*)d_in[0];
    const float* Q     = (const float*)d_in[1];
    const float* cmask = (const float*)d_in[2];
    const float* qmask = (const float*)d_in[3];
    const float* w     = (const float*)d_in[4];
    float* out = (float*)d_out;

    // workspace layout (floats); total ~10.2M floats (~41 MB)
    float* ws = (float*)d_ws;
    float* S_g      = ws;                                    // B*LC*LQ
    float* rowmax_g = S_g + (size_t)B_ * LC_ * LQ_;          // B*LC
    float* rowsum_g = rowmax_g + (size_t)B_ * LC_;           // B*LC
    float* pmax     = rowsum_g + (size_t)B_ * LC_;           // B*32*LQ
    float* psum     = pmax + (size_t)B_ * 32 * LQ_;          // B*32*LQ
    float* colmax_g = psum + (size_t)B_ * 32 * LQ_;          // B*LQ
    float* colsum_g = colmax_g + (size_t)B_ * LQ_;           // B*LQ
    float* sq_g     = colsum_g + (size_t)B_ * LQ_;           // B*LQ
    float* sc_g     = sq_g + (size_t)B_ * LQ_;               // B*LC
    float* T2_g     = sc_g + (size_t)B_ * LC_;               // B*D*LQ

    k0_sq<<<dim3(B_ * LQ_ / 256), 256, 0, stream>>>(Q, w, sq_g);
    k0_sc<<<dim3(B_ * LC_ / 256), 256, 0, stream>>>(C, w, sc_g);
    k1_S<<<dim3(LC_ / 32, B_), 256, 0, stream>>>(C, Q, qmask, w, sc_g, sq_g,
                                                 S_g, rowmax_g, rowsum_g);
    k2a<<<dim3(32, B_), 128, 0, stream>>>(S_g, cmask, pmax, psum);
    k2b<<<dim3(B_), 128, 0, stream>>>(pmax, psum, colmax_g, colsum_g);
    k3_T2<<<dim3(LQ_ / 32, B_), 256, 0, stream>>>(C, S_g, cmask, colmax_g, colsum_g, T2_g);
    k4_out<<<dim3(LC_ / 64, B_), 256, 0, stream>>>(C, Q, qmask, S_g, rowmax_g,
                                                   rowsum_g, T2_g, out);
}

// Round 2
// 265.811 us; speedup vs baseline: 3.5607x; 3.5607x over previous
//
#include <hip/hip_runtime.h>
#include <cstdint>
#include <cstddef>

#define B_  64
#define D_  128
#define LC_ 1024
#define LQ_ 128
#define NEGV (-1e30f)
#define NINF (-3.402823466e38f)

typedef short s16x8 __attribute__((ext_vector_type(8)));
typedef float f32x4 __attribute__((ext_vector_type(4)));

__device__ __forceinline__ unsigned short f2bf(float x) {
    union { float f; unsigned u; } v; v.f = x;
    unsigned r = v.u + 0x7fffu + ((v.u >> 16) & 1u);   // RNE
    return (unsigned short)(r >> 16);
}

// ---------------------------------------------------------------------------
// kT_C: CWt[b][c][d] = bf16(w_m[d] * C[b][d][c])   (transpose + scale + cvt)
// ---------------------------------------------------------------------------
__global__ __launch_bounds__(256) void kT_C(const float* __restrict__ C,
                                            const float* __restrict__ w,
                                            unsigned short* __restrict__ CWt) {
    __shared__ float tile[32][33];
    int t = threadIdx.x;
    int c0 = blockIdx.x * 32, d0 = blockIdx.y * 32, b = blockIdx.z;
    int cc = t & 31, r8 = t >> 5;
#pragma unroll
    for (int i = 0; i < 4; i++) {
        int dd = r8 + 8 * i;
        tile[dd][cc] = C[((size_t)b * D_ + d0 + dd) * LC_ + c0 + cc] * w[2 * D_ + d0 + dd];
    }
    __syncthreads();
#pragma unroll
    for (int i = 0; i < 4; i++) {
        int c2 = r8 + 8 * i;
        CWt[((size_t)b * LC_ + c0 + c2) * D_ + d0 + cc] = f2bf(tile[cc][c2]);
    }
}

// ---------------------------------------------------------------------------
// kT_Q: Qt[b][q][d] = bf16(Q[b][d][q])
// ---------------------------------------------------------------------------
__global__ __launch_bounds__(256) void kT_Q(const float* __restrict__ Q,
                                            unsigned short* __restrict__ Qt) {
    __shared__ float tile[32][33];
    int t = threadIdx.x;
    int q0 = blockIdx.x * 32, d0 = blockIdx.y * 32, b = blockIdx.z;
    int qq = t & 31, r8 = t >> 5;
#pragma unroll
    for (int i = 0; i < 4; i++) {
        int dd = r8 + 8 * i;
        tile[dd][qq] = Q[((size_t)b * D_ + d0 + dd) * LQ_ + q0 + qq];
    }
    __syncthreads();
#pragma unroll
    for (int i = 0; i < 4; i++) {
        int q2 = r8 + 8 * i;
        Qt[((size_t)b * LQ_ + q0 + q2) * D_ + d0 + qq] = f2bf(tile[qq][q2]);
    }
}

// ---------------------------------------------------------------------------
// k0: s_q[b,q], s_c[b,c] (fp32 dot products, memory-trivial)
// ---------------------------------------------------------------------------
__global__ __launch_bounds__(256) void k0_sq(const float* __restrict__ Q,
                                             const float* __restrict__ w,
                                             float* __restrict__ sq_g) {
    int idx = blockIdx.x * 256 + threadIdx.x;
    int b = idx >> 7, q = idx & 127;
    float s = 0.f;
    for (int d = 0; d < D_; d++) s += Q[((size_t)b * D_ + d) * LQ_ + q] * w[d];
    sq_g[idx] = s;
}

__global__ __launch_bounds__(256) void k0_sc(const float* __restrict__ C,
                                             const float* __restrict__ w,
                                             float* __restrict__ sc_g) {
    int idx = blockIdx.x * 256 + threadIdx.x;
    int b = idx >> 10, c = idx & 1023;
    float s = 0.f;
    for (int d = 0; d < D_; d++) s += C[((size_t)b * D_ + d) * LC_ + c] * w[D_ + d];
    sc_g[idx] = s;
}

// ---------------------------------------------------------------------------
// kA_S: S[b,c,q] = sum_d CWt[c][d]*Qt[q][d] + s_c + s_q   (MFMA bf16)
// grid (LC/128, B), block 256 (4 waves, each 32 c-rows x 128 q)
// ---------------------------------------------------------------------------
__global__ __launch_bounds__(256) void kA_S(const unsigned short* __restrict__ CWt,
                                            const unsigned short* __restrict__ Qt,
                                            const float* __restrict__ sc_g,
                                            const float* __restrict__ sq_g,
                                            float* __restrict__ S_g) {
    __shared__ unsigned short Aw[128 * 136];   // stride 136 bf16 = 68 dw (2-way max)
    __shared__ unsigned short Bq[128 * 136];
    __shared__ float sc_l[128], sq_l[128];
    int t = threadIdx.x;
    int b = blockIdx.y, c0 = blockIdx.x * 128;
    if (t < 128) {
        sc_l[t] = sc_g[b * LC_ + c0 + t];
        sq_l[t] = sq_g[b * LQ_ + t];
    }
    const uint4* gA = (const uint4*)(CWt + ((size_t)b * LC_ + c0) * D_);
    const uint4* gB = (const uint4*)(Qt + (size_t)b * LQ_ * D_);
#pragma unroll
    for (int i = 0; i < 8; i++) {
        int g = i * 256 + t;
        int row = g >> 4, col = g & 15;
        *(uint4*)&Aw[row * 136 + col * 8] = gA[g];
        *(uint4*)&Bq[row * 136 + col * 8] = gB[g];
    }
    __syncthreads();
    int w = t >> 6, l = t & 63, quad = l >> 4, lp = l & 15;
    int w32 = w * 32;
    f32x4 zero = {0.f, 0.f, 0.f, 0.f};
    f32x4 acc[2][8];
#pragma unroll
    for (int mc = 0; mc < 2; mc++)
#pragma unroll
        for (int qt = 0; qt < 8; qt++) acc[mc][qt] = zero;

#pragma unroll
    for (int ks = 0; ks < 4; ks++) {
        s16x8 a[2], bb[8];
        a[0] = *(const s16x8*)&Aw[(w32 + lp) * 136 + ks * 32 + quad * 8];
        a[1] = *(const s16x8*)&Aw[(w32 + 16 + lp) * 136 + ks * 32 + quad * 8];
#pragma unroll
        for (int qt = 0; qt < 8; qt++)
            bb[qt] = *(const s16x8*)&Bq[(qt * 16 + lp) * 136 + ks * 32 + quad * 8];
#pragma unroll
        for (int mc = 0; mc < 2; mc++)
#pragma unroll
            for (int qt = 0; qt < 8; qt++)
                acc[mc][qt] = __builtin_amdgcn_mfma_f32_16x16x32_bf16(a[mc], bb[qt], acc[mc][qt], 0, 0, 0);
    }
#pragma unroll
    for (int mc = 0; mc < 2; mc++)
#pragma unroll
        for (int i = 0; i < 4; i++) {
            int cl = w32 + mc * 16 + quad * 4 + i;
            float scv = sc_l[cl];
            size_t rb = ((size_t)b * LC_ + c0 + cl) * LQ_;
#pragma unroll
            for (int qt = 0; qt < 8; qt++) {
                int q = qt * 16 + lp;
                S_g[rb + q] = acc[mc][qt][i] + scv + sq_l[q];
            }
        }
}

// ---------------------------------------------------------------------------
// krow: rowmax/rowsum over q (masked). One wave per row.
// ---------------------------------------------------------------------------
__global__ __launch_bounds__(256) void krow(const float* __restrict__ S_g,
                                            const float* __restrict__ qmask,
                                            float* __restrict__ rowmax_g,
                                            float* __restrict__ rowsum_g) {
    int t = threadIdx.x, w = t >> 6, l = t & 63;
    int b = blockIdx.y;
    int r = blockIdx.x * 4 + w;
    size_t rb = ((size_t)b * LC_ + r) * LQ_;
    float v0 = S_g[rb + l] + (1.0f - qmask[b * LQ_ + l]) * NEGV;
    float v1 = S_g[rb + 64 + l] + (1.0f - qmask[b * LQ_ + 64 + l]) * NEGV;
    float m = fmaxf(v0, v1);
#pragma unroll
    for (int off = 1; off < 64; off <<= 1) m = fmaxf(m, __shfl_xor(m, off, 64));
    float s = __expf(v0 - m) + __expf(v1 - m);
#pragma unroll
    for (int off = 1; off < 64; off <<= 1) s += __shfl_xor(s, off, 64);
    if (l == 0) { rowmax_g[b * LC_ + r] = m; rowsum_g[b * LC_ + r] = s; }
}

// ---------------------------------------------------------------------------
// k2a/k2b: column softmax stats over c (masked)
// ---------------------------------------------------------------------------
__global__ __launch_bounds__(128) void k2a(const float* __restrict__ S_g,
                                           const float* __restrict__ cmask,
                                           float* __restrict__ pmax,
                                           float* __restrict__ psum) {
    int q = threadIdx.x;
    int b = blockIdx.y;
    int chunk = blockIdx.x;
    int cbase = chunk * 32;
    float m = NINF, s = 0.f;
    for (int cc = 0; cc < 32; cc++) {
        int c = cbase + cc;
        float v = S_g[((size_t)b * LC_ + c) * LQ_ + q] + (1.0f - cmask[b * LC_ + c]) * NEGV;
        float mn = fmaxf(m, v);
        s = s * __expf(m - mn) + __expf(v - mn);
        m = mn;
    }
    pmax[((size_t)b * 32 + chunk) * LQ_ + q] = m;
    psum[((size_t)b * 32 + chunk) * LQ_ + q] = s;
}

__global__ __launch_bounds__(128) void k2b(const float* __restrict__ pmax,
                                           const float* __restrict__ psum,
                                           float* __restrict__ colmax_g,
                                           float* __restrict__ colsum_g) {
    int q = threadIdx.x;
    int b = blockIdx.x;
    float m = NINF;
    for (int j = 0; j < 32; j++) m = fmaxf(m, pmax[((size_t)b * 32 + j) * LQ_ + q]);
    float s = 0.f;
    for (int j = 0; j < 32; j++)
        s += psum[((size_t)b * 32 + j) * LQ_ + q] * __expf(pmax[((size_t)b * 32 + j) * LQ_ + q] - m);
    colmax_g[b * LQ_ + q] = m;
    colsum_g[b * LQ_ + q] = s;
}

// ---------------------------------------------------------------------------
// kB_T2: T2p[kc][b][d][q] = sum_{c in chunk} exp(S+cm-colmax)[c][q] * C[d][c]
// grid (4, B), block 256. Split-K partials, MFMA bf16.
// ---------------------------------------------------------------------------
__global__ __launch_bounds__(256) void kB_T2(const float* __restrict__ C,
                                             const float* __restrict__ S_g,
                                             const float* __restrict__ cmask,
                                             const float* __restrict__ colmax_g,
                                             float* __restrict__ T2p) {
    __shared__ unsigned short Ca[128 * 40];   // [d][c] stride 40 bf16 = 20 dw
    __shared__ unsigned short Et[128 * 40];   // [q][c]
    __shared__ float cm_l[128];
    int t = threadIdx.x;
    int b = blockIdx.y, kc = blockIdx.x;
    int cbase = kc * 256;
    if (t < 128) cm_l[t] = colmax_g[b * LQ_ + t];
    int w = t >> 6, l = t & 63, quad = l >> 4, lp = l & 15;
    int w32 = w * 32;
    f32x4 zero = {0.f, 0.f, 0.f, 0.f};
    f32x4 acc[2][8];
#pragma unroll
    for (int mc = 0; mc < 2; mc++)
#pragma unroll
        for (int qt = 0; qt < 8; qt++) acc[mc][qt] = zero;
    __syncthreads();

    for (int cb = 0; cb < 256; cb += 32) {
        {   // stage Ca: 128 d-rows x 32 c (fp32 -> bf16)
            int d = t >> 1, half = t & 1;
            const float4* src = (const float4*)(C + ((size_t)b * D_ + d) * LC_ + cbase + cb + half * 16);
            unsigned short* dst = &Ca[d * 40 + half * 16];
#pragma unroll
            for (int j = 0; j < 4; j++) {
                float4 v = src[j];
                ushort4 o;
                o.x = f2bf(v.x); o.y = f2bf(v.y); o.z = f2bf(v.z); o.w = f2bf(v.w);
                *(ushort4*)&dst[j * 4] = o;
            }
        }
        {   // stage Et: exp(S + cm - colmax), transposed to [q][c]
            int cc = t >> 3, qb = (t & 7) * 16;
            int cg = cbase + cb + cc;
            float cmv = (1.0f - cmask[b * LC_ + cg]) * NEGV;
            const float4* src = (const float4*)(S_g + ((size_t)b * LC_ + cg) * LQ_ + qb);
#pragma unroll
            for (int j = 0; j < 4; j++) {
                float4 v = src[j];
                int q = qb + j * 4;
                Et[(q + 0) * 40 + cc] = f2bf(__expf(v.x + cmv - cm_l[q + 0]));
                Et[(q + 1) * 40 + cc] = f2bf(__expf(v.y + cmv - cm_l[q + 1]));
                Et[(q + 2) * 40 + cc] = f2bf(__expf(v.z + cmv - cm_l[q + 2]));
                Et[(q + 3) * 40 + cc] = f2bf(__expf(v.w + cmv - cm_l[q + 3]));
            }
        }
        __syncthreads();
        s16x8 a[2], bb[8];
        a[0] = *(const s16x8*)&Ca[(w32 + lp) * 40 + quad * 8];
        a[1] = *(const s16x8*)&Ca[(w32 + 16 + lp) * 40 + quad * 8];
#pragma unroll
        for (int qt = 0; qt < 8; qt++)
            bb[qt] = *(const s16x8*)&Et[(qt * 16 + lp) * 40 + quad * 8];
#pragma unroll
        for (int mc = 0; mc < 2; mc++)
#pragma unroll
            for (int qt = 0; qt < 8; qt++)
                acc[mc][qt] = __builtin_amdgcn_mfma_f32_16x16x32_bf16(a[mc], bb[qt], acc[mc][qt], 0, 0, 0);
        __syncthreads();
    }
    size_t base = (size_t)kc * ((size_t)B_ * D_ * LQ_) + (size_t)b * D_ * LQ_;
#pragma unroll
    for (int mc = 0; mc < 2; mc++)
#pragma unroll
        for (int i = 0; i < 4; i++) {
            int d = w32 + mc * 16 + quad * 4 + i;
#pragma unroll
            for (int qt = 0; qt < 8; qt++)
                T2p[base + (size_t)d * LQ_ + qt * 16 + lp] = acc[mc][qt][i];
        }
}

// ---------------------------------------------------------------------------
// k3b: T2s[b][d][q] = (sum_4 T2p) / colsum[b][q]   (fp32)
// ---------------------------------------------------------------------------
__global__ __launch_bounds__(256) void k3b(const float* __restrict__ T2p,
                                           const float* __restrict__ colsum_g,
                                           float* __restrict__ T2s) {
    int idx = blockIdx.x * 256 + threadIdx.x;
    const int N = B_ * D_ * LQ_;
    int b = idx >> 14, q = idx & 127;
    float s = T2p[idx] + T2p[idx + N] + T2p[idx + 2 * N] + T2p[idx + 3 * N];
    T2s[idx] = s / colsum_g[b * LQ_ + q];
}

// ---------------------------------------------------------------------------
// kC_out: accA[d][c] = sum_q Q[d][q]*S1n[c][q]; accB[d][c] = sum_q T2s[d][q]*S1n[c][q]
// out[b] = [C ; A^T ; C.*A^T ; C.*Bt^T]. grid (LC/128, B), block 256.
// ---------------------------------------------------------------------------
__global__ __launch_bounds__(256) void kC_out(const float* __restrict__ C,
                                              const float* __restrict__ Q,
                                              const float* __restrict__ qmask,
                                              const float* __restrict__ S_g,
                                              const float* __restrict__ rowmax_g,
                                              const float* __restrict__ rowsum_g,
                                              const float* __restrict__ T2s,
                                              float* __restrict__ out) {
    __shared__ unsigned short S1[128 * 136];   // [c][q] bf16, ri folded in
    __shared__ unsigned short Aq[128 * 72];    // [d][q-chunk 64]
    __shared__ unsigned short At[128 * 72];
    __shared__ float rm_l[128], ri_l[128], qm_l[128];
    int t = threadIdx.x;
    int b = blockIdx.y, c0 = blockIdx.x * 128;
    if (t < 128) {
        rm_l[t] = rowmax_g[b * LC_ + c0 + t];
        ri_l[t] = 1.0f / rowsum_g[b * LC_ + c0 + t];
        qm_l[t] = qmask[b * LQ_ + t];
    }
    __syncthreads();
    {   // stage S1 = exp(S + qm - rowmax) * (1/rowsum), bf16
        int cc = t >> 1, qb = (t & 1) * 64;
        float rm = rm_l[cc], ri = ri_l[cc];
        const float4* src = (const float4*)(S_g + ((size_t)b * LC_ + c0 + cc) * LQ_ + qb);
        unsigned short* dst = &S1[cc * 136 + qb];
#pragma unroll
        for (int j = 0; j < 16; j++) {
            float4 v = src[j];
            int q = qb + j * 4;
            ushort4 o;
            o.x = f2bf(__expf(v.x + (1.0f - qm_l[q + 0]) * NEGV - rm) * ri);
            o.y = f2bf(__expf(v.y + (1.0f - qm_l[q + 1]) * NEGV - rm) * ri);
            o.z = f2bf(__expf(v.z + (1.0f - qm_l[q + 2]) * NEGV - rm) * ri);
            o.w = f2bf(__expf(v.w + (1.0f - qm_l[q + 3]) * NEGV - rm) * ri);
            *(ushort4*)&dst[j * 4] = o;
        }
    }
    int w = t >> 6, l = t & 63, quad = l >> 4, lp = l & 15;
    int w32 = w * 32;
    f32x4 zero = {0.f, 0.f, 0.f, 0.f};
    f32x4 accA[2][8], accB[2][8];
#pragma unroll
    for (int mc = 0; mc < 2; mc++)
#pragma unroll
        for (int nt = 0; nt < 8; nt++) { accA[mc][nt] = zero; accB[mc][nt] = zero; }

    for (int kq = 0; kq < 2; kq++) {
        __syncthreads();
        {   // stage Aq/At q-chunk (fp32 -> bf16)
            int d = t >> 1, qoff = (t & 1) * 32;
            const float4* sq4 = (const float4*)(Q + ((size_t)b * D_ + d) * LQ_ + kq * 64 + qoff);
            const float4* st4 = (const float4*)(T2s + ((size_t)b * D_ + d) * LQ_ + kq * 64 + qoff);
            unsigned short* dq = &Aq[d * 72 + qoff];
            unsigned short* dt = &At[d * 72 + qoff];
#pragma unroll
            for (int j = 0; j < 8; j++) {
                float4 v = sq4[j];
                ushort4 o;
                o.x = f2bf(v.x); o.y = f2bf(v.y); o.z = f2bf(v.z); o.w = f2bf(v.w);
                *(ushort4*)&dq[j * 4] = o;
                float4 u = st4[j];
                ushort4 p;
                p.x = f2bf(u.x); p.y = f2bf(u.y); p.z = f2bf(u.z); p.w = f2bf(u.w);
                *(ushort4*)&dt[j * 4] = p;
            }
        }
        __syncthreads();
#pragma unroll
        for (int ks = 0; ks < 2; ks++) {
            s16x8 aq[2], at[2], bb[8];
            aq[0] = *(const s16x8*)&Aq[(w32 + lp) * 72 + ks * 32 + quad * 8];
            aq[1] = *(const s16x8*)&Aq[(w32 + 16 + lp) * 72 + ks * 32 + quad * 8];
            at[0] = *(const s16x8*)&At[(w32 + lp) * 72 + ks * 32 + quad * 8];
            at[1] = *(const s16x8*)&At[(w32 + 16 + lp) * 72 + ks * 32 + quad * 8];
#pragma unroll
            for (int nt = 0; nt < 8; nt++)
                bb[nt] = *(const s16x8*)&S1[(nt * 16 + lp) * 136 + kq * 64 + ks * 32 + quad * 8];
#pragma unroll
            for (int mc = 0; mc < 2; mc++)
#pragma unroll
                for (int nt = 0; nt < 8; nt++) {
                    accA[mc][nt] = __builtin_amdgcn_mfma_f32_16x16x32_bf16(aq[mc], bb[nt], accA[mc][nt], 0, 0, 0);
                    accB[mc][nt] = __builtin_amdgcn_mfma_f32_16x16x32_bf16(at[mc], bb[nt], accB[mc][nt], 0, 0, 0);
                }
        }
    }
    const size_t DL = (size_t)D_ * LC_;
#pragma unroll
    for (int mc = 0; mc < 2; mc++)
#pragma unroll
        for (int i = 0; i < 4; i++) {
            int d = w32 + mc * 16 + quad * 4 + i;
            const float* Crow = C + ((size_t)b * D_ + d) * LC_ + c0;
            size_t ob = ((size_t)b * 4 * D_ + d) * LC_ + c0;
#pragma unroll
            for (int nt = 0; nt < 8; nt++) {
                int c = nt * 16 + lp;
                float cv = Crow[c];
                float a = accA[mc][nt][i];
                float bt = accB[mc][nt][i];
                out[ob + c] = cv;
                out[ob + DL + c] = a;
                out[ob + 2 * DL + c] = cv * a;
                out[ob + 3 * DL + c] = cv * bt;
            }
        }
}

// ---------------------------------------------------------------------------
extern "C" void kernel_launch(void* const* d_in, const int* in_sizes, int n_in,
                              void* d_out, int out_size, void* d_ws, size_t ws_size,
                              hipStream_t stream) {
    const float* C     = (const float*)d_in[0];
    const float* Q     = (const float*)d_in[1];
    const float* cmask = (const float*)d_in[2];
    const float* qmask = (const float*)d_in[3];
    const float* w     = (const float*)d_in[4];
    float* out = (float*)d_out;

    // workspace layout: fp32 region then bf16 region (~76 MB total)
    float* ws = (float*)d_ws;
    float* S_g      = ws;                                    // B*LC*LQ      = 8388608
    float* rowmax_g = S_g + (size_t)B_ * LC_ * LQ_;          // B*LC
    float* rowsum_g = rowmax_g + (size_t)B_ * LC_;
    float* pmax     = rowsum_g + (size_t)B_ * LC_;           // B*32*LQ
    float* psum     = pmax + (size_t)B_ * 32 * LQ_;
    float* colmax_g = psum + (size_t)B_ * 32 * LQ_;          // B*LQ
    float* colsum_g = colmax_g + (size_t)B_ * LQ_;
    float* sq_g     = colsum_g + (size_t)B_ * LQ_;
    float* sc_g     = sq_g + (size_t)B_ * LQ_;               // B*LC
    float* T2p      = sc_g + (size_t)B_ * LC_;               // 4*B*D*LQ     = 4194304
    float* T2s      = T2p + (size_t)4 * B_ * D_ * LQ_;       // B*D*LQ       = 1048576
    unsigned short* CWt = (unsigned short*)(T2s + (size_t)B_ * D_ * LQ_);  // B*LC*D bf16
    unsigned short* Qt  = CWt + (size_t)B_ * LC_ * D_;                      // B*LQ*D bf16

    kT_C<<<dim3(LC_ / 32, D_ / 32, B_), 256, 0, stream>>>(C, w, CWt);
    kT_Q<<<dim3(LQ_ / 32, D_ / 32, B_), 256, 0, stream>>>(Q, Qt);
    k0_sq<<<dim3(B_ * LQ_ / 256), 256, 0, stream>>>(Q, w, sq_g);
    k0_sc<<<dim3(B_ * LC_ / 256), 256, 0, stream>>>(C, w, sc_g);
    kA_S<<<dim3(LC_ / 128, B_), 256, 0, stream>>>(CWt, Qt, sc_g, sq_g, S_g);
    krow<<<dim3(LC_ / 4, B_), 256, 0, stream>>>(S_g, qmask, rowmax_g, rowsum_g);
    k2a<<<dim3(32, B_), 128, 0, stream>>>(S_g, cmask, pmax, psum);
    k2b<<<dim3(B_), 128, 0, stream>>>(pmax, psum, colmax_g, colsum_g);
    kB_T2<<<dim3(4, B_), 256, 0, stream>>>(C, S_g, cmask, colmax_g, T2p);
    k3b<<<dim3(B_ * D_ * LQ_ / 256), 256, 0, stream>>>(T2p, colsum_g, T2s);
    kC_out<<<dim3(LC_ / 128, B_), 256, 0, stream>>>(C, Q, qmask, S_g, rowmax_g,
                                                    rowsum_g, T2s, out);
}

// Round 3
// 254.811 us; speedup vs baseline: 3.7144x; 1.0432x over previous
//
#include <hip/hip_runtime.h>
#include <cstdint>
#include <cstddef>

#define B_  64
#define D_  128
#define LC_ 1024
#define LQ_ 128
#define NEGV (-1e30f)
#define NINF (-3.402823466e38f)

typedef short s16x8 __attribute__((ext_vector_type(8)));
typedef float f32x4 __attribute__((ext_vector_type(4)));

__device__ __forceinline__ unsigned short f2bf(float x) {
    union { float f; unsigned u; } v; v.f = x;
    unsigned r = v.u + 0x7fffu + ((v.u >> 16) & 1u);   // RNE
    return (unsigned short)(r >> 16);
}
__device__ __forceinline__ float bf2f(unsigned short x) {
    union { unsigned u; float f; } v; v.u = ((unsigned)x) << 16;
    return v.f;
}

// ---------------------------------------------------------------------------
// kT_C: CWt[b][c][d] = bf16(w_m[d]*C[b][d][c]) ; Cb[b][d][c] = bf16(C) ;
//       sc[b][c] = sum_d C*w_c
// grid (LC/32, B), 256 thr
// ---------------------------------------------------------------------------
__global__ __launch_bounds__(256) void kT_C(const float* __restrict__ C,
                                            const float* __restrict__ w,
                                            unsigned short* __restrict__ CWt,
                                            unsigned short* __restrict__ Cb,
                                            float* __restrict__ sc_g) {
    __shared__ float tile[32][33];
    __shared__ float wc_l[128], wm_l[128];
    __shared__ float red[8][32];
    int t = threadIdx.x;
    int b = blockIdx.y, c0 = blockIdx.x * 32;
    if (t < 128) { wc_l[t] = w[D_ + t]; wm_l[t] = w[2 * D_ + t]; }
    __syncthreads();
    float scp = 0.f;
    int cc = t & 31, db = t >> 5;
    for (int ch = 0; ch < 4; ch++) {
#pragma unroll
        for (int i = 0; i < 4; i++) {
            int dl = db * 4 + i;
            float v = C[((size_t)(b * D_ + ch * 32 + dl)) * LC_ + c0 + cc];
            tile[dl][cc] = v;
            scp += v * wc_l[ch * 32 + dl];
        }
        __syncthreads();
        {
            int c2 = t >> 3, ds = (t & 7) * 4;
            ushort4 o;
            o.x = f2bf(tile[ds + 0][c2] * wm_l[ch * 32 + ds + 0]);
            o.y = f2bf(tile[ds + 1][c2] * wm_l[ch * 32 + ds + 1]);
            o.z = f2bf(tile[ds + 2][c2] * wm_l[ch * 32 + ds + 2]);
            o.w = f2bf(tile[ds + 3][c2] * wm_l[ch * 32 + ds + 3]);
            *(ushort4*)&CWt[((size_t)(b * LC_ + c0 + c2)) * D_ + ch * 32 + ds] = o;
        }
        {
            int d2 = t >> 3, cs = (t & 7) * 4;
            ushort4 o;
            o.x = f2bf(tile[d2][cs + 0]);
            o.y = f2bf(tile[d2][cs + 1]);
            o.z = f2bf(tile[d2][cs + 2]);
            o.w = f2bf(tile[d2][cs + 3]);
            *(ushort4*)&Cb[((size_t)(b * D_ + ch * 32 + d2)) * LC_ + c0 + cs] = o;
        }
        __syncthreads();
    }
    red[db][cc] = scp;
    __syncthreads();
    if (t < 32) {
        float s = 0.f;
#pragma unroll
        for (int j = 0; j < 8; j++) s += red[j][t];
        sc_g[b * LC_ + c0 + t] = s;
    }
}

// ---------------------------------------------------------------------------
// kT_Q: Qt[b][q][d] = bf16(Q[b][d][q]) ; Qb[b][d][q] = bf16(Q) ; sq = sum Q*w_q
// grid (LQ/32, B), 256 thr
// ---------------------------------------------------------------------------
__global__ __launch_bounds__(256) void kT_Q(const float* __restrict__ Q,
                                            const float* __restrict__ w,
                                            unsigned short* __restrict__ Qt,
                                            unsigned short* __restrict__ Qb,
                                            float* __restrict__ sq_g) {
    __shared__ float tile[32][33];
    __shared__ float wq_l[128];
    __shared__ float red[8][32];
    int t = threadIdx.x;
    int b = blockIdx.y, q0 = blockIdx.x * 32;
    if (t < 128) wq_l[t] = w[t];
    __syncthreads();
    float sqp = 0.f;
    int qq = t & 31, db = t >> 5;
    for (int ch = 0; ch < 4; ch++) {
#pragma unroll
        for (int i = 0; i < 4; i++) {
            int dl = db * 4 + i;
            float v = Q[((size_t)(b * D_ + ch * 32 + dl)) * LQ_ + q0 + qq];
            tile[dl][qq] = v;
            sqp += v * wq_l[ch * 32 + dl];
        }
        __syncthreads();
        {
            int q2 = t >> 3, ds = (t & 7) * 4;
            ushort4 o;
            o.x = f2bf(tile[ds + 0][q2]);
            o.y = f2bf(tile[ds + 1][q2]);
            o.z = f2bf(tile[ds + 2][q2]);
            o.w = f2bf(tile[ds + 3][q2]);
            *(ushort4*)&Qt[((size_t)(b * LQ_ + q0 + q2)) * D_ + ch * 32 + ds] = o;
        }
        {
            int d2 = t >> 3, qs = (t & 7) * 4;
            ushort4 o;
            o.x = f2bf(tile[d2][qs + 0]);
            o.y = f2bf(tile[d2][qs + 1]);
            o.z = f2bf(tile[d2][qs + 2]);
            o.w = f2bf(tile[d2][qs + 3]);
            *(ushort4*)&Qb[((size_t)(b * D_ + ch * 32 + d2)) * LQ_ + q0 + qs] = o;
        }
        __syncthreads();
    }
    red[db][qq] = sqp;
    __syncthreads();
    if (t < 32) {
        float s = 0.f;
#pragma unroll
        for (int j = 0; j < 8; j++) s += red[j][t];
        sq_g[b * LQ_ + q0 + t] = s;
    }
}

// ---------------------------------------------------------------------------
// kA_S: S tile via MFMA (direct-global fragments); row softmax fused in-wave;
// writes S1 bf16 (normalized), g[c]=rowsum*exp(rowmax+cmv), col partial stats.
// grid (LC/128, B), 256 thr (4 waves x 32 c-rows)
// ---------------------------------------------------------------------------
__global__ __launch_bounds__(256) void kA_S(const unsigned short* __restrict__ CWt,
                                            const unsigned short* __restrict__ Qt,
                                            const float* __restrict__ sc_g,
                                            const float* __restrict__ sq_g,
                                            const float* __restrict__ cmask,
                                            const float* __restrict__ qmask,
                                            unsigned short* __restrict__ S1b,
                                            float* __restrict__ g_g,
                                            float* __restrict__ pmax_g,
                                            float* __restrict__ psum_g) {
    __shared__ unsigned short S1t[128 * 136];  // stride 136: 16B-aligned rows, 2-way max
    __shared__ float sc_l[128], sq_l[128], cmv_l[128], qmv_l[128];
    int t = threadIdx.x;
    int b = blockIdx.y, c0 = blockIdx.x * 128;
    if (t < 128) {
        sc_l[t] = sc_g[b * LC_ + c0 + t];
        sq_l[t] = sq_g[b * LQ_ + t];
        cmv_l[t] = (1.0f - cmask[b * LC_ + c0 + t]) * NEGV;
        qmv_l[t] = (1.0f - qmask[b * LQ_ + t]) * NEGV;
    }
    __syncthreads();
    int wv = t >> 6, l = t & 63, quad = l >> 4, lp = l & 15;
    int w32 = wv * 32;
    f32x4 zero = {0.f, 0.f, 0.f, 0.f};
    f32x4 acc[2][8];
#pragma unroll
    for (int mc = 0; mc < 2; mc++)
#pragma unroll
        for (int qt = 0; qt < 8; qt++) acc[mc][qt] = zero;

#pragma unroll
    for (int ks = 0; ks < 4; ks++) {
        s16x8 a[2], bb[8];
        a[0] = *(const s16x8*)&CWt[((size_t)(b * LC_ + c0 + w32 + lp)) * D_ + ks * 32 + quad * 8];
        a[1] = *(const s16x8*)&CWt[((size_t)(b * LC_ + c0 + w32 + 16 + lp)) * D_ + ks * 32 + quad * 8];
#pragma unroll
        for (int qt = 0; qt < 8; qt++)
            bb[qt] = *(const s16x8*)&Qt[((size_t)(b * LQ_ + qt * 16 + lp)) * D_ + ks * 32 + quad * 8];
#pragma unroll
        for (int mc = 0; mc < 2; mc++)
#pragma unroll
            for (int qt = 0; qt < 8; qt++)
                acc[mc][qt] = __builtin_amdgcn_mfma_f32_16x16x32_bf16(a[mc], bb[qt], acc[mc][qt], 0, 0, 0);
    }
    // add sc + sq
#pragma unroll
    for (int mc = 0; mc < 2; mc++)
#pragma unroll
        for (int qt = 0; qt < 8; qt++)
#pragma unroll
            for (int i = 0; i < 4; i++)
                acc[mc][qt][i] += sc_l[w32 + mc * 16 + quad * 4 + i] + sq_l[qt * 16 + lp];

    float qmv_r[8];
#pragma unroll
    for (int qt = 0; qt < 8; qt++) qmv_r[qt] = qmv_l[qt * 16 + lp];

    // row stats (softmax over q) via 16-lane butterflies; write g
    float rm_r[2][4], ri_r[2][4];
#pragma unroll
    for (int mc = 0; mc < 2; mc++)
#pragma unroll
        for (int i = 0; i < 4; i++) {
            float m = NINF;
#pragma unroll
            for (int qt = 0; qt < 8; qt++) m = fmaxf(m, acc[mc][qt][i] + qmv_r[qt]);
#pragma unroll
            for (int off = 1; off < 16; off <<= 1) m = fmaxf(m, __shfl_xor(m, off, 64));
            float s = 0.f;
#pragma unroll
            for (int qt = 0; qt < 8; qt++) s += __expf(acc[mc][qt][i] + qmv_r[qt] - m);
#pragma unroll
            for (int off = 1; off < 16; off <<= 1) s += __shfl_xor(s, off, 64);
            rm_r[mc][i] = m;
            ri_r[mc][i] = 1.0f / s;
            int row = w32 + mc * 16 + quad * 4 + i;
            if (lp == 0) g_g[b * LC_ + c0 + row] = s * __expf(m + cmv_l[row]);
        }

    // column partial stats over this wave's 32 rows (no qmask — matches ref)
    float cmv_r[2][4];
#pragma unroll
    for (int mc = 0; mc < 2; mc++)
#pragma unroll
        for (int i = 0; i < 4; i++) cmv_r[mc][i] = cmv_l[w32 + mc * 16 + quad * 4 + i];
    int chunk = blockIdx.x * 4 + wv;
#pragma unroll
    for (int qt = 0; qt < 8; qt++) {
        float cm = NINF;
#pragma unroll
        for (int mc = 0; mc < 2; mc++)
#pragma unroll
            for (int i = 0; i < 4; i++) cm = fmaxf(cm, acc[mc][qt][i] + cmv_r[mc][i]);
        cm = fmaxf(cm, __shfl_xor(cm, 16, 64));
        cm = fmaxf(cm, __shfl_xor(cm, 32, 64));
        float cs = 0.f;
#pragma unroll
        for (int mc = 0; mc < 2; mc++)
#pragma unroll
            for (int i = 0; i < 4; i++) cs += __expf(acc[mc][qt][i] + cmv_r[mc][i] - cm);
        cs += __shfl_xor(cs, 16, 64);
        cs += __shfl_xor(cs, 32, 64);
        if (l < 16) {
            pmax_g[((size_t)(b * 32 + chunk)) * LQ_ + qt * 16 + lp] = cm;
            psum_g[((size_t)(b * 32 + chunk)) * LQ_ + qt * 16 + lp] = cs;
        }
    }

    // S1 = exp(S+qmv-rm)*ri  -> LDS transpose buffer -> coalesced global bf16
#pragma unroll
    for (int mc = 0; mc < 2; mc++)
#pragma unroll
        for (int qt = 0; qt < 8; qt++)
#pragma unroll
            for (int i = 0; i < 4; i++) {
                int row = w32 + mc * 16 + quad * 4 + i;
                float s1 = __expf(acc[mc][qt][i] + qmv_r[qt] - rm_r[mc][i]) * ri_r[mc][i];
                S1t[row * 136 + qt * 16 + lp] = f2bf(s1);
            }
    __syncthreads();
    {
        int row = t >> 1, qh = (t & 1) * 64;
        const uint4* src = (const uint4*)&S1t[row * 136 + qh];
        uint4* dst = (uint4*)&S1b[((size_t)(b * LC_ + c0 + row)) * LQ_ + qh];
#pragma unroll
        for (int j = 0; j < 8; j++) dst[j] = src[j];
    }
}

// ---------------------------------------------------------------------------
// k2b: reduce 32 col-partial chunks -> hq = exp(-colmax), ci = 1/colsum
// ---------------------------------------------------------------------------
__global__ __launch_bounds__(128) void k2b(const float* __restrict__ pmax,
                                           const float* __restrict__ psum,
                                           float* __restrict__ hq_g,
                                           float* __restrict__ ci_g) {
    int q = threadIdx.x, b = blockIdx.x;
    float m = NINF;
    for (int j = 0; j < 32; j++) m = fmaxf(m, pmax[((size_t)(b * 32 + j)) * LQ_ + q]);
    float s = 0.f;
    for (int j = 0; j < 32; j++)
        s += psum[((size_t)(b * 32 + j)) * LQ_ + q] * __expf(pmax[((size_t)(b * 32 + j)) * LQ_ + q] - m);
    hq_g[b * LQ_ + q] = __expf(-m);
    ci_g[b * LQ_ + q] = 1.0f / s;
}

// ---------------------------------------------------------------------------
// kB_T2: T2p[kc][b][d][q] = sum_{c in K-chunk} Cb[d][c] * (S1[c][q]*g[c]*hq[q])
// grid (8 = 4 K-splits x 2 N-splits, B), 256 thr
// ---------------------------------------------------------------------------
__global__ __launch_bounds__(256) void kB_T2(const unsigned short* __restrict__ Cb,
                                             const unsigned short* __restrict__ S1b,
                                             const float* __restrict__ g_g,
                                             const float* __restrict__ hq_g,
                                             float* __restrict__ T2p) {
    __shared__ unsigned short Ew[64 * 72];   // [q][c-chunk 64], stride 72
    __shared__ float h_l[64];
    int t = threadIdx.x;
    int b = blockIdx.y;
    int kc = blockIdx.x >> 1, nq = blockIdx.x & 1;
    int q0 = nq * 64, cbase = kc * 256;
    if (t < 64) h_l[t] = hq_g[b * LQ_ + q0 + t];
    int wv = t >> 6, l = t & 63, quad = l >> 4, lp = l & 15;
    int w32 = wv * 32;
    f32x4 zero = {0.f, 0.f, 0.f, 0.f};
    f32x4 acc[2][4];
#pragma unroll
    for (int mc = 0; mc < 2; mc++)
#pragma unroll
        for (int nt = 0; nt < 4; nt++) acc[mc][nt] = zero;
    __syncthreads();

    for (int sub = 0; sub < 4; sub++) {
        int csub = cbase + sub * 64;
#pragma unroll
        for (int r = 0; r < 2; r++) {
            int cr = (t >> 3) + 32 * r;
            int qof = (t & 7) * 8;
            float gv = g_g[b * LC_ + csub + cr];
            uint4 v = *(const uint4*)&S1b[((size_t)(b * LC_ + csub + cr)) * LQ_ + q0 + qof];
            const unsigned short* pu = (const unsigned short*)&v;
#pragma unroll
            for (int j = 0; j < 8; j++)
                Ew[(qof + j) * 72 + cr] = f2bf(bf2f(pu[j]) * gv * h_l[qof + j]);
        }
        __syncthreads();
#pragma unroll
        for (int ks = 0; ks < 2; ks++) {
            s16x8 a[2], bb[4];
            a[0] = *(const s16x8*)&Cb[((size_t)(b * D_ + w32 + lp)) * LC_ + csub + ks * 32 + quad * 8];
            a[1] = *(const s16x8*)&Cb[((size_t)(b * D_ + w32 + 16 + lp)) * LC_ + csub + ks * 32 + quad * 8];
#pragma unroll
            for (int nt = 0; nt < 4; nt++)
                bb[nt] = *(const s16x8*)&Ew[(nt * 16 + lp) * 72 + ks * 32 + quad * 8];
#pragma unroll
            for (int mc = 0; mc < 2; mc++)
#pragma unroll
                for (int nt = 0; nt < 4; nt++)
                    acc[mc][nt] = __builtin_amdgcn_mfma_f32_16x16x32_bf16(a[mc], bb[nt], acc[mc][nt], 0, 0, 0);
        }
        __syncthreads();
    }
#pragma unroll
    for (int mc = 0; mc < 2; mc++)
#pragma unroll
        for (int i = 0; i < 4; i++) {
            int d = w32 + mc * 16 + quad * 4 + i;
#pragma unroll
            for (int nt = 0; nt < 4; nt++)
                T2p[(((size_t)kc * B_ + b) * D_ + d) * LQ_ + q0 + nt * 16 + lp] = acc[mc][nt][i];
        }
}

// ---------------------------------------------------------------------------
// k3b: T2b bf16 = (sum of 4 K-split partials) / colsum
// ---------------------------------------------------------------------------
__global__ __launch_bounds__(256) void k3b(const float* __restrict__ T2p,
                                           const float* __restrict__ ci_g,
                                           unsigned short* __restrict__ T2b) {
    int idx = blockIdx.x * 256 + threadIdx.x;
    const size_t N = (size_t)B_ * D_ * LQ_;
    int b = idx >> 14, q = idx & 127;
    float s = T2p[idx] + T2p[idx + N] + T2p[idx + 2 * N] + T2p[idx + 3 * N];
    T2b[idx] = f2bf(s * ci_g[b * LQ_ + q]);
}

// ---------------------------------------------------------------------------
// kC_out: LDS-free. accA = S1·Q^T, accB = S1·T2^T via direct-global fragments;
// epilogue writes [C ; A^T ; C.*A^T ; C.*Bt^T] feature-major.
// grid (LC/128, B), 256 thr
// ---------------------------------------------------------------------------
__global__ __launch_bounds__(256) void kC_out(const float* __restrict__ C,
                                              const unsigned short* __restrict__ Qb,
                                              const unsigned short* __restrict__ T2b,
                                              const unsigned short* __restrict__ S1b,
                                              float* __restrict__ out) {
    int t = threadIdx.x;
    int b = blockIdx.y, c0 = blockIdx.x * 128;
    int wv = t >> 6, l = t & 63, quad = l >> 4, lp = l & 15;
    int w32 = wv * 32;
    f32x4 zero = {0.f, 0.f, 0.f, 0.f};
    f32x4 accA[2][8], accB[2][8];
#pragma unroll
    for (int mc = 0; mc < 2; mc++)
#pragma unroll
        for (int nt = 0; nt < 8; nt++) { accA[mc][nt] = zero; accB[mc][nt] = zero; }

#pragma unroll
    for (int ks = 0; ks < 4; ks++) {
        s16x8 aq[2], at[2], bb[8];
        aq[0] = *(const s16x8*)&Qb[((size_t)(b * D_ + w32 + lp)) * LQ_ + ks * 32 + quad * 8];
        aq[1] = *(const s16x8*)&Qb[((size_t)(b * D_ + w32 + 16 + lp)) * LQ_ + ks * 32 + quad * 8];
        at[0] = *(const s16x8*)&T2b[((size_t)(b * D_ + w32 + lp)) * LQ_ + ks * 32 + quad * 8];
        at[1] = *(const s16x8*)&T2b[((size_t)(b * D_ + w32 + 16 + lp)) * LQ_ + ks * 32 + quad * 8];
#pragma unroll
        for (int nt = 0; nt < 8; nt++)
            bb[nt] = *(const s16x8*)&S1b[((size_t)(b * LC_ + c0 + nt * 16 + lp)) * LQ_ + ks * 32 + quad * 8];
#pragma unroll
        for (int mc = 0; mc < 2; mc++)
#pragma unroll
            for (int nt = 0; nt < 8; nt++) {
                accA[mc][nt] = __builtin_amdgcn_mfma_f32_16x16x32_bf16(aq[mc], bb[nt], accA[mc][nt], 0, 0, 0);
                accB[mc][nt] = __builtin_amdgcn_mfma_f32_16x16x32_bf16(at[mc], bb[nt], accB[mc][nt], 0, 0, 0);
            }
    }
    const size_t DL = (size_t)D_ * LC_;
#pragma unroll
    for (int mc = 0; mc < 2; mc++)
#pragma unroll
        for (int i = 0; i < 4; i++) {
            int d = w32 + mc * 16 + quad * 4 + i;
            const float* Crow = C + ((size_t)(b * D_ + d)) * LC_ + c0;
            size_t ob = ((size_t)(b * 4 * D_ + d)) * LC_ + c0;
#pragma unroll
            for (int nt = 0; nt < 8; nt++) {
                int c = nt * 16 + lp;
                float cv = Crow[c];
                float a = accA[mc][nt][i];
                float bt = accB[mc][nt][i];
                out[ob + c] = cv;
                out[ob + DL + c] = a;
                out[ob + 2 * DL + c] = cv * a;
                out[ob + 3 * DL + c] = cv * bt;
            }
        }
}

// ---------------------------------------------------------------------------
extern "C" void kernel_launch(void* const* d_in, const int* in_sizes, int n_in,
                              void* d_out, int out_size, void* d_ws, size_t ws_size,
                              hipStream_t stream) {
    const float* C     = (const float*)d_in[0];
    const float* Q     = (const float*)d_in[1];
    const float* cmask = (const float*)d_in[2];
    const float* qmask = (const float*)d_in[3];
    const float* w     = (const float*)d_in[4];
    float* out = (float*)d_out;

    // workspace layout: bf16 region then fp32 region (~77 MB)
    unsigned short* us = (unsigned short*)d_ws;
    unsigned short* S1b = us;                                   // B*LC*LQ
    unsigned short* CWt = S1b + (size_t)B_ * LC_ * LQ_;         // B*LC*D
    unsigned short* Cb  = CWt + (size_t)B_ * LC_ * D_;          // B*D*LC
    unsigned short* Qt  = Cb  + (size_t)B_ * D_ * LC_;          // B*LQ*D
    unsigned short* Qb  = Qt  + (size_t)B_ * LQ_ * D_;          // B*D*LQ
    unsigned short* T2b = Qb  + (size_t)B_ * D_ * LQ_;          // B*D*LQ
    float* fp = (float*)(T2b + (size_t)B_ * D_ * LQ_);
    float* T2p    = fp;                                         // 4*B*D*LQ
    float* sc_g   = T2p + (size_t)4 * B_ * D_ * LQ_;            // B*LC
    float* g_g    = sc_g + (size_t)B_ * LC_;                    // B*LC
    float* pmax_g = g_g + (size_t)B_ * LC_;                     // B*32*LQ
    float* psum_g = pmax_g + (size_t)B_ * 32 * LQ_;             // B*32*LQ
    float* sq_g   = psum_g + (size_t)B_ * 32 * LQ_;             // B*LQ
    float* hq_g   = sq_g + (size_t)B_ * LQ_;                    // B*LQ
    float* ci_g   = hq_g + (size_t)B_ * LQ_;                    // B*LQ

    kT_C<<<dim3(LC_ / 32, B_), 256, 0, stream>>>(C, w, CWt, Cb, sc_g);
    kT_Q<<<dim3(LQ_ / 32, B_), 256, 0, stream>>>(Q, w, Qt, Qb, sq_g);
    kA_S<<<dim3(LC_ / 128, B_), 256, 0, stream>>>(CWt, Qt, sc_g, sq_g, cmask, qmask,
                                                  S1b, g_g, pmax_g, psum_g);
    k2b<<<dim3(B_), 128, 0, stream>>>(pmax_g, psum_g, hq_g, ci_g);
    kB_T2<<<dim3(8, B_), 256, 0, stream>>>(Cb, S1b, g_g, hq_g, T2p);
    k3b<<<dim3(B_ * D_ * LQ_ / 256), 256, 0, stream>>>(T2p, ci_g, T2b);
    kC_out<<<dim3(LC_ / 128, B_), 256, 0, stream>>>(C, Qb, T2b, S1b, out);
}